// Round 5
// baseline (2087.055 us; speedup 1.0000x reference)
//
#include <hip/hip_runtime.h>
#include <hip/hip_bf16.h>

#define HD 128
#define RD 64
#define H3 384

__device__ __forceinline__ float silu_f(float x) {
    return x / (1.0f + __expf(-x));
}

// condG[g,h] = z[g]@z_w + z_b + t_emb[g]@t_w + t_b
__global__ __launch_bounds__(128) void cond_kernel(const float* __restrict__ z, const float* __restrict__ t,
                            const float* __restrict__ z_w, const float* __restrict__ z_b,
                            const float* __restrict__ t_w, const float* __restrict__ t_b,
                            float* __restrict__ condG) {
    int g = blockIdx.x;
    int k = threadIdx.x;
    __shared__ float zr[128];
    __shared__ float te[64];
    zr[k] = z[g * 128 + k];
    if (k < 32) {
        float f = __expf(-9.2103403719761836f * (float)k / 31.0f);
        float e = t[g] * f;
        te[k] = sinf(e);
        te[32 + k] = cosf(e);
    }
    __syncthreads();
    float acc = z_b[k] + t_b[k];
    #pragma unroll 8
    for (int i = 0; i < 128; ++i) acc += zr[i] * z_w[i * 128 + k];
    #pragma unroll 8
    for (int i = 0; i < 64; ++i) acc += te[i] * t_w[i * 128 + k];
    condG[g * 128 + k] = acc;
}

// s[n,h] = atom_embed[types[n], h] + condG[batch[n], h]   (cond folded in)
__global__ void init_kernel(const int* __restrict__ types, const float* __restrict__ emb,
                            const float* __restrict__ condG, const int* __restrict__ batch,
                            float* __restrict__ s, int N_) {
    int i = blockIdx.x * blockDim.x + threadIdx.x;
    if (i < N_ * HD) {
        int n = i >> 7;
        int k = i & 127;
        s[i] = emb[types[n] * HD + k] + condG[batch[n] * 128 + k];
    }
}

// per-edge geometry: cart, dist, unit (original edge order, temporary buffers)
__global__ void geom_kernel(const float* __restrict__ coords, const int* __restrict__ srcI,
                            const int* __restrict__ dstI, const int* __restrict__ batch,
                            const float* __restrict__ lattice, const float* __restrict__ offs,
                            float* __restrict__ dist, float* __restrict__ unit, int E_) {
    int e = blockIdx.x * blockDim.x + threadIdx.x;
    if (e >= E_) return;
    int sn = srcI[e], dn = dstI[e];
    float f0 = coords[dn * 3 + 0] - coords[sn * 3 + 0] + offs[e * 3 + 0];
    float f1 = coords[dn * 3 + 1] - coords[sn * 3 + 1] + offs[e * 3 + 1];
    float f2 = coords[dn * 3 + 2] - coords[sn * 3 + 2] + offs[e * 3 + 2];
    const float* Lg = lattice + batch[sn] * 9;
    float c0 = f0 * Lg[0] + f1 * Lg[3] + f2 * Lg[6];
    float c1 = f0 * Lg[1] + f1 * Lg[4] + f2 * Lg[7];
    float c2 = f0 * Lg[2] + f1 * Lg[5] + f2 * Lg[8];
    float nrm = sqrtf(c0 * c0 + c1 * c1 + c2 * c2);
    dist[e] = fmaxf(nrm, 1e-8f);
    float inv = 1.0f / fmaxf(nrm, 1e-12f);
    unit[e * 3 + 0] = c0 * inv;
    unit[e * 3 + 1] = c1 * inv;
    unit[e * 3 + 2] = c2 * inv;
}

// --- counting sort of edges by dst (edge_index is layer-invariant) ---
__global__ void hist_kernel(const int* __restrict__ dstI, int* __restrict__ cnt, int E_) {
    int e = blockIdx.x * blockDim.x + threadIdx.x;
    if (e < E_) atomicAdd(&cnt[dstI[e]], 1);
}

// exclusive prefix sum (single block Hillis-Steele over chunks)
__global__ __launch_bounds__(1024) void scan_kernel(const int* __restrict__ cnt, int* __restrict__ cur, int n) {
    __shared__ int tmp[1024];
    __shared__ int carry_s;
    if (threadIdx.x == 0) carry_s = 0;
    __syncthreads();
    for (int base = 0; base < n; base += 1024) {
        int i = base + threadIdx.x;
        int x = (i < n) ? cnt[i] : 0;
        tmp[threadIdx.x] = x;
        __syncthreads();
        for (int off = 1; off < 1024; off <<= 1) {
            int y = (threadIdx.x >= off) ? tmp[threadIdx.x - off] : 0;
            __syncthreads();
            tmp[threadIdx.x] += y;
            __syncthreads();
        }
        if (i < n) cur[i] = carry_s + tmp[threadIdx.x] - x;   // exclusive
        __syncthreads();
        if (threadIdx.x == 0) carry_s += tmp[1023];
        __syncthreads();
    }
}

// scatter edges into dst-sorted order, reordering all per-edge data
__global__ void scatter_kernel(const int* __restrict__ srcI, const int* __restrict__ dstI,
                               const float* __restrict__ dist, const float* __restrict__ unit,
                               int* __restrict__ cur,
                               float* __restrict__ dist_s, float* __restrict__ unit_s,
                               int* __restrict__ src_s, int* __restrict__ dst_s, int E_) {
    int e = blockIdx.x * blockDim.x + threadIdx.x;
    if (e >= E_) return;
    int d = dstI[e];
    int p = atomicAdd(&cur[d], 1);
    dist_s[p] = dist[e];
    unit_s[p * 3 + 0] = unit[e * 3 + 0];
    unit_s[p * 3 + 1] = unit[e * 3 + 1];
    unit_s[p * 3 + 2] = unit[e * 3 + 2];
    src_s[p] = srcI[e];
    dst_s[p] = d;
}

// phi = silu(s@w1+b1)@w2+b2.  s already includes cond.  GEMM1 acts via scalar loads.
#define NPB 16
__global__ __launch_bounds__(128, 4) void phi_kernel(const float* __restrict__ s,
                           const float* __restrict__ w1, const float* __restrict__ b1,
                           const float* __restrict__ w2, const float* __restrict__ b2,
                           float* __restrict__ phi, int N_) {
    int n0 = blockIdx.x * NPB;
    int k = threadIdx.x;
    __shared__ float hh[NPB][128];
    const float* sp[NPB];
    #pragma unroll
    for (int j = 0; j < NPB; ++j) {
        int n = n0 + j; if (n >= N_) n = N_ - 1;
        sp[j] = s + (size_t)n * 128;
    }
    float acc[NPB];
    #pragma unroll
    for (int j = 0; j < NPB; ++j) acc[j] = b1[k];
    for (int h = 0; h < 128; h += 4) {
        float wa = w1[h * 128 + k];
        float wb = w1[(h + 1) * 128 + k];
        float wc = w1[(h + 2) * 128 + k];
        float wd = w1[(h + 3) * 128 + k];
        #pragma unroll
        for (int j = 0; j < NPB; ++j) {
            float x0 = sp[j][h], x1 = sp[j][h + 1], x2 = sp[j][h + 2], x3 = sp[j][h + 3];
            acc[j] = fmaf(x3, wd, fmaf(x2, wc, fmaf(x1, wb, fmaf(x0, wa, acc[j]))));
        }
    }
    #pragma unroll
    for (int j = 0; j < NPB; ++j) hh[j][k] = silu_f(acc[j]);
    __syncthreads();
    float p0[NPB], p1[NPB], p2[NPB];
    #pragma unroll
    for (int j = 0; j < NPB; ++j) { p0[j] = b2[k]; p1[j] = b2[128 + k]; p2[j] = b2[256 + k]; }
    for (int h = 0; h < 128; h += 4) {
        float wa0 = w2[h * 384 + k],       wa1 = w2[(h + 1) * 384 + k];
        float wa2 = w2[(h + 2) * 384 + k], wa3 = w2[(h + 3) * 384 + k];
        float wb0 = w2[h * 384 + 128 + k],       wb1 = w2[(h + 1) * 384 + 128 + k];
        float wb2 = w2[(h + 2) * 384 + 128 + k], wb3 = w2[(h + 3) * 384 + 128 + k];
        float wc0 = w2[h * 384 + 256 + k],       wc1 = w2[(h + 1) * 384 + 256 + k];
        float wc2 = w2[(h + 2) * 384 + 256 + k], wc3 = w2[(h + 3) * 384 + 256 + k];
        #pragma unroll
        for (int j = 0; j < NPB; ++j) {
            const float4 x = *reinterpret_cast<const float4*>(&hh[j][h]);
            p0[j] = fmaf(x.w, wa3, fmaf(x.z, wa2, fmaf(x.y, wa1, fmaf(x.x, wa0, p0[j]))));
            p1[j] = fmaf(x.w, wb3, fmaf(x.z, wb2, fmaf(x.y, wb1, fmaf(x.x, wb0, p1[j]))));
            p2[j] = fmaf(x.w, wc3, fmaf(x.z, wc2, fmaf(x.y, wc1, fmaf(x.x, wc0, p2[j]))));
        }
    }
    #pragma unroll
    for (int j = 0; j < NPB; ++j) {
        int n = n0 + j;
        if (n < N_) {
            size_t o = (size_t)n * 384;
            phi[o + k] = p0[j];
            phi[o + 128 + k] = p1[j];
            phi[o + 256 + k] = p2[j];
        }
    }
}

// fused edge message on dst-sorted edges: register-segmented accumulation, flush on dst change.
// Accumulates into s and vn (vn pre-initialized with v).
#define EPB 128
__global__ __launch_bounds__(512) void edge_kernel(
    const float* __restrict__ phi, const float* __restrict__ v,
    const float* __restrict__ dist_s, const float* __restrict__ unit_s,
    const int* __restrict__ src_s, const int* __restrict__ dst_s,
    const float* __restrict__ rw, const float* __restrict__ rb,
    float* __restrict__ s, float* __restrict__ vn, int E_) {
    __shared__ unsigned short w_lds[RD * H3];  // bf16, 49152 B
    __shared__ float rbf_lds[4][4][RD];        // 4096 B
    for (int i = threadIdx.x; i < RD * H3; i += 512) {
        __hip_bfloat16 hb = __float2bfloat16(rw[i]);
        w_lds[i] = *reinterpret_cast<unsigned short*>(&hb);
    }
    int sub = threadIdx.x >> 7;   // 0..3, each sub owns 32 contiguous sorted edges
    int col = threadIdx.x & 127;
    float b0 = rb[col], b1 = rb[128 + col], b2 = rb[256 + col];
    int span0 = blockIdx.x * EPB + sub * 32;
    float as = 0.0f, ad0 = 0.0f, ad1 = 0.0f, ad2 = 0.0f;
    int rd = -1;
    for (int it = 0; it < 8; ++it) {
        int eb = span0 + it * 4;
        __syncthreads();  // w_lds ready (iter 0); rbf_lds no longer read (iter > 0)
        {
            int r = col & 63;
            int jbase = col >> 6;  // 0 or 1
            #pragma unroll
            for (int jj = 0; jj < 2; ++jj) {
                int j = jbase + 2 * jj;
                int e = eb + j;
                float val = 0.0f;
                if (e < E_) {
                    float d = dist_s[e];
                    float c = 6.0f * (float)r / 63.0f;
                    float tt = d - c;
                    val = __expf(-(64.0f / 6.0f) * tt * tt);
                }
                rbf_lds[sub][j][r] = val;
            }
        }
        __syncthreads();
        float f[4][3] = {};
        #pragma unroll 4
        for (int r = 0; r < 64; ++r) {
            float w0 = __uint_as_float(((unsigned)w_lds[r * 384 + col]) << 16);
            float w1 = __uint_as_float(((unsigned)w_lds[r * 384 + 128 + col]) << 16);
            float w2 = __uint_as_float(((unsigned)w_lds[r * 384 + 256 + col]) << 16);
            #pragma unroll
            for (int j = 0; j < 4; ++j) {
                float rbv = rbf_lds[sub][j][r];
                f[j][0] += rbv * w0;
                f[j][1] += rbv * w1;
                f[j][2] += rbv * w2;
            }
        }
        #pragma unroll
        for (int j = 0; j < 4; ++j) {
            int e = eb + j;
            if (e >= E_) break;
            int dn = dst_s[e];
            if (dn != rd) {  // wave-uniform: dst uniform across the sub's lanes
                if (rd >= 0) {
                    atomicAdd(&s[(size_t)rd * 128 + col], as);
                    atomicAdd(&vn[(size_t)rd * 384 + col], ad0);
                    atomicAdd(&vn[(size_t)rd * 384 + 128 + col], ad1);
                    atomicAdd(&vn[(size_t)rd * 384 + 256 + col], ad2);
                }
                as = ad0 = ad1 = ad2 = 0.0f;
                rd = dn;
            }
            int sn = src_s[e];
            const float* phr = phi + (size_t)sn * 384;
            const float* vr = v + (size_t)sn * 384;
            float x0 = phr[col] * (f[j][0] + b0);
            float x1 = phr[128 + col] * (f[j][1] + b1);
            float x2 = phr[256 + col] * (f[j][2] + b2);
            float u0 = unit_s[e * 3 + 0], u1 = unit_s[e * 3 + 1], u2 = unit_s[e * 3 + 2];
            as += x0;
            ad0 += x1 * vr[col] + x2 * u0;
            ad1 += x1 * vr[128 + col] + x2 * u1;
            ad2 += x1 * vr[256 + col] + x2 * u2;
        }
    }
    if (rd >= 0) {
        atomicAdd(&s[(size_t)rd * 128 + col], as);
        atomicAdd(&vn[(size_t)rd * 384 + col], ad0);
        atomicAdd(&vn[(size_t)rd * 384 + 128 + col], ad1);
        atomicAdd(&vn[(size_t)rd * 384 + 256 + col], ad2);
    }
}

// update block: 8 nodes per block, 128 threads (k = col).
// GEMM activations via scalar loads (vn, s are wave-uniform rows from prev kernels);
// LDS only for per-lane intermediates Vn and a1l. Epilogue: global RMW of v, s (+cond).
__global__ __launch_bounds__(128, 4) void update_kernel(
    const float* __restrict__ U, const float* __restrict__ Vw,
    const float* __restrict__ w1, const float* __restrict__ b1,
    const float* __restrict__ w2, const float* __restrict__ b2,
    float* __restrict__ s, float* __restrict__ v, const float* __restrict__ vn,
    const float* __restrict__ condG, const int* __restrict__ batch, int addcond, int N_) {
    const int k = threadIdx.x;           // 0..127
    const int n0 = blockIdx.x * 8;
    __shared__ float vn_sh[8][128];      // Vn (per-lane produced, broadcast consumed)
    __shared__ float al_sh[8][128];      // a1l
    const float* ap[8];
    #pragma unroll
    for (int j = 0; j < 8; ++j) {
        int n = n0 + j; if (n >= N_) n = N_ - 1;
        ap[j] = vn + (size_t)n * 384;
    }
    float Uv[8][3] = {}, Vv[8][3] = {};
    for (int h = 0; h < 128; h += 4) {
        float u0 = U[h * 128 + k],       u1 = U[(h + 1) * 128 + k];
        float u2 = U[(h + 2) * 128 + k], u3 = U[(h + 3) * 128 + k];
        float q0 = Vw[h * 128 + k],       q1 = Vw[(h + 1) * 128 + k];
        float q2 = Vw[(h + 2) * 128 + k], q3 = Vw[(h + 3) * 128 + k];
        #pragma unroll
        for (int j = 0; j < 8; ++j) {
            #pragma unroll
            for (int c = 0; c < 3; ++c) {
                const float* a = ap[j] + c * 128 + h;
                float x0 = a[0], x1 = a[1], x2 = a[2], x3 = a[3];   // uniform -> s_load
                Uv[j][c] = fmaf(x3, u3, fmaf(x2, u2, fmaf(x1, u1, fmaf(x0, u0, Uv[j][c]))));
                Vv[j][c] = fmaf(x3, q3, fmaf(x2, q2, fmaf(x1, q1, fmaf(x0, q0, Vv[j][c]))));
            }
        }
    }
    float dot[8];
    #pragma unroll
    for (int j = 0; j < 8; ++j) {
        dot[j] = Uv[j][0] * Vv[j][0] + Uv[j][1] * Vv[j][1] + Uv[j][2] * Vv[j][2];
        vn_sh[j][k] = sqrtf(Vv[j][0] * Vv[j][0] + Vv[j][1] * Vv[j][1] + Vv[j][2] * Vv[j][2] + 1e-8f);
    }
    __syncthreads();
    const float* sp[8];
    #pragma unroll
    for (int j = 0; j < 8; ++j) {
        int n = n0 + j; if (n >= N_) n = N_ - 1;
        sp[j] = s + (size_t)n * 128;
    }
    float a1[8];
    #pragma unroll
    for (int j = 0; j < 8; ++j) a1[j] = b1[k];
    for (int f = 0; f < 128; f += 4) {
        float w0 = w1[f * 128 + k],        wv1 = w1[(f + 1) * 128 + k];
        float w2v = w1[(f + 2) * 128 + k], w3 = w1[(f + 3) * 128 + k];
        #pragma unroll
        for (int j = 0; j < 8; ++j) {
            float x0 = sp[j][f], x1 = sp[j][f + 1], x2 = sp[j][f + 2], x3 = sp[j][f + 3];  // s_load
            a1[j] = fmaf(x3, w3, fmaf(x2, w2v, fmaf(x1, wv1, fmaf(x0, w0, a1[j]))));
        }
    }
    for (int f = 0; f < 128; f += 4) {
        float w0 = w1[(128 + f) * 128 + k],        wv1 = w1[(129 + f) * 128 + k];
        float w2v = w1[(130 + f) * 128 + k], w3 = w1[(131 + f) * 128 + k];
        #pragma unroll
        for (int j = 0; j < 8; ++j) {
            const float4 x = *reinterpret_cast<const float4*>(&vn_sh[j][f]);
            a1[j] = fmaf(x.w, w3, fmaf(x.z, w2v, fmaf(x.y, wv1, fmaf(x.x, w0, a1[j]))));
        }
    }
    #pragma unroll
    for (int j = 0; j < 8; ++j) al_sh[j][k] = silu_f(a1[j]);
    __syncthreads();
    float a0r[8], aHr[8], a2r[8];
    #pragma unroll
    for (int j = 0; j < 8; ++j) { a0r[j] = b2[k]; aHr[j] = b2[128 + k]; a2r[j] = b2[256 + k]; }
    for (int f = 0; f < 128; f += 4) {
        float wa0 = w2[f * 384 + k],       wa1 = w2[(f + 1) * 384 + k];
        float wa2 = w2[(f + 2) * 384 + k], wa3 = w2[(f + 3) * 384 + k];
        float wb0 = w2[f * 384 + 128 + k],       wb1 = w2[(f + 1) * 384 + 128 + k];
        float wb2 = w2[(f + 2) * 384 + 128 + k], wb3 = w2[(f + 3) * 384 + 128 + k];
        float wc0 = w2[f * 384 + 256 + k],       wc1 = w2[(f + 1) * 384 + 256 + k];
        float wc2 = w2[(f + 2) * 384 + 256 + k], wc3 = w2[(f + 3) * 384 + 256 + k];
        #pragma unroll
        for (int j = 0; j < 8; ++j) {
            const float4 x = *reinterpret_cast<const float4*>(&al_sh[j][f]);
            a0r[j] = fmaf(x.w, wa3, fmaf(x.z, wa2, fmaf(x.y, wa1, fmaf(x.x, wa0, a0r[j]))));
            aHr[j] = fmaf(x.w, wb3, fmaf(x.z, wb2, fmaf(x.y, wb1, fmaf(x.x, wb0, aHr[j]))));
            a2r[j] = fmaf(x.w, wc3, fmaf(x.z, wc2, fmaf(x.y, wc1, fmaf(x.x, wc0, a2r[j]))));
        }
    }
    #pragma unroll
    for (int j = 0; j < 8; ++j) {
        int n = n0 + j;
        if (n >= N_) continue;   // uniform branch
        size_t vo = (size_t)n * 384;
        #pragma unroll
        for (int c = 0; c < 3; ++c)
            v[vo + c * 128 + k] = vn[vo + c * 128 + k] + a0r[j] * Uv[j][c];
        float cadd = addcond ? condG[(size_t)batch[n] * 128 + k] : 0.0f;
        s[(size_t)n * 128 + k] += aHr[j] * dot[j] + a2r[j] + cadd;
    }
}

// output heads: 8 nodes per block
#define HPB 8
__global__ __launch_bounds__(128, 4) void heads_kernel(
    const float* __restrict__ s,
    const float* __restrict__ hc_w1, const float* __restrict__ hc_b1,
    const float* __restrict__ hc_w2, const float* __restrict__ hc_b2,
    const float* __restrict__ ht_w1, const float* __restrict__ ht_b1,
    const float* __restrict__ ht_w2, const float* __restrict__ ht_b2,
    float* __restrict__ outc, float* __restrict__ outt, int N_) {
    int n0 = blockIdx.x * HPB;
    int k = threadIdx.x;
    __shared__ float h1[HPB][128];
    __shared__ float h2[HPB][128];
    const float* sp[HPB];
    #pragma unroll
    for (int j = 0; j < HPB; ++j) {
        int n = n0 + j; if (n >= N_) n = N_ - 1;
        sp[j] = s + (size_t)n * 128;
    }
    float a[HPB], b[HPB];
    #pragma unroll
    for (int j = 0; j < HPB; ++j) { a[j] = hc_b1[k]; b[j] = ht_b1[k]; }
    for (int h = 0; h < 128; h += 4) {
        float wa0 = hc_w1[h * 128 + k],       wa1 = hc_w1[(h + 1) * 128 + k];
        float wa2 = hc_w1[(h + 2) * 128 + k], wa3 = hc_w1[(h + 3) * 128 + k];
        float wb0 = ht_w1[h * 128 + k],       wb1 = ht_w1[(h + 1) * 128 + k];
        float wb2 = ht_w1[(h + 2) * 128 + k], wb3 = ht_w1[(h + 3) * 128 + k];
        #pragma unroll
        for (int j = 0; j < HPB; ++j) {
            float x0 = sp[j][h], x1 = sp[j][h + 1], x2 = sp[j][h + 2], x3 = sp[j][h + 3];  // s_load
            a[j] = fmaf(x3, wa3, fmaf(x2, wa2, fmaf(x1, wa1, fmaf(x0, wa0, a[j]))));
            b[j] = fmaf(x3, wb3, fmaf(x2, wb2, fmaf(x1, wb1, fmaf(x0, wb0, b[j]))));
        }
    }
    #pragma unroll
    for (int j = 0; j < HPB; ++j) {
        h1[j][k] = silu_f(a[j]);
        h2[j][k] = silu_f(b[j]);
    }
    __syncthreads();
    if (k < 101) {
        for (int j = 0; j < HPB; ++j) {
            int n = n0 + j;
            if (n >= N_) break;
            float c = ht_b2[k];
            #pragma unroll 4
            for (int h = 0; h < 128; ++h) c += h2[j][h] * ht_w2[h * 101 + k];
            outt[(size_t)n * 101 + k] = c;
        }
    }
    if (k < 3) {
        for (int j = 0; j < HPB; ++j) {
            int n = n0 + j;
            if (n >= N_) break;
            float c = hc_b2[k];
            #pragma unroll 4
            for (int h = 0; h < 128; ++h) c += h1[j][h] * hc_w2[h * 3 + k];
            outc[(size_t)n * 3 + k] = c;
        }
    }
}

extern "C" void kernel_launch(void* const* d_in, const int* in_sizes, int n_in,
                              void* d_out, int out_size, void* d_ws, size_t ws_size,
                              hipStream_t stream) {
    const float* coords  = (const float*)d_in[0];
    const int*   types   = (const int*)d_in[1];
    const float* z       = (const float*)d_in[2];
    const float* t       = (const float*)d_in[3];
    const int*   eidx    = (const int*)d_in[4];
    const int*   batch   = (const int*)d_in[5];
    const float* lattice = (const float*)d_in[6];
    const float* offs    = (const float*)d_in[7];
    const float* aemb    = (const float*)d_in[8];
    const float* z_w     = (const float*)d_in[9];
    const float* z_b     = (const float*)d_in[10];
    const float* t_w     = (const float*)d_in[11];
    const float* t_b     = (const float*)d_in[12];
    const float* msg_w1  = (const float*)d_in[13];
    const float* msg_b1  = (const float*)d_in[14];
    const float* msg_w2  = (const float*)d_in[15];
    const float* msg_b2  = (const float*)d_in[16];
    const float* rbf_w   = (const float*)d_in[17];
    const float* rbf_b   = (const float*)d_in[18];
    const float* Um      = (const float*)d_in[19];
    const float* Vm      = (const float*)d_in[20];
    const float* upd_w1  = (const float*)d_in[21];
    const float* upd_b1  = (const float*)d_in[22];
    const float* upd_w2  = (const float*)d_in[23];
    const float* upd_b2  = (const float*)d_in[24];
    const float* hc_w1   = (const float*)d_in[25];
    const float* hc_b1   = (const float*)d_in[26];
    const float* hc_w2   = (const float*)d_in[27];
    const float* hc_b2   = (const float*)d_in[28];
    const float* ht_w1   = (const float*)d_in[29];
    const float* ht_b1   = (const float*)d_in[30];
    const float* ht_w2   = (const float*)d_in[31];
    const float* ht_b2   = (const float*)d_in[32];

    const int N = in_sizes[1];
    const int G = in_sizes[3];
    const int E = in_sizes[4] / 2;
    const int* srcI = eidx;
    const int* dstI = eidx + E;

    char* ws = (char*)d_ws;
    auto alloc = [&](size_t bytes) {
        char* p = ws;
        ws += (bytes + 255) & ~(size_t)255;
        return p;
    };
    float* s_buf   = (float*)alloc((size_t)N * HD * 4);
    float* v_buf   = (float*)alloc((size_t)N * H3 * 4);
    float* vn_buf  = (float*)alloc((size_t)N * H3 * 4);
    float* phi_buf = (float*)alloc((size_t)N * H3 * 4);
    float* condG   = (float*)alloc((size_t)G * HD * 4);
    float* dist_s  = (float*)alloc((size_t)E * 4);
    float* unit_s  = (float*)alloc((size_t)E * 3 * 4);
    int*   src_s   = (int*)alloc((size_t)E * 4);
    int*   dst_s   = (int*)alloc((size_t)E * 4);
    int*   cur     = (int*)alloc((size_t)N * 4);
    // temporaries (original-order geometry) aliased into phi_buf (not yet live)
    float* dist_t  = phi_buf;                 // E floats
    float* unit_t  = phi_buf + E;             // 3E floats

    hipMemsetAsync(v_buf, 0, (size_t)N * H3 * 4, stream);
    hipMemsetAsync(cur, 0, (size_t)N * 4, stream);
    cond_kernel<<<G, 128, 0, stream>>>(z, t, z_w, z_b, t_w, t_b, condG);
    init_kernel<<<(N * HD + 255) / 256, 256, 0, stream>>>(types, aemb, condG, batch, s_buf, N);
    geom_kernel<<<(E + 255) / 256, 256, 0, stream>>>(coords, srcI, dstI, batch, lattice, offs, dist_t, unit_t, E);
    // counting sort by dst (reused across all 4 layers)
    hist_kernel<<<(E + 255) / 256, 256, 0, stream>>>(dstI, cur, E);
    {
        int* cnt2 = (int*)(phi_buf + 4 * (size_t)E);  // after dist_t/unit_t region
        hipMemcpyAsync(cnt2, cur, (size_t)N * 4, hipMemcpyDeviceToDevice, stream);
        scan_kernel<<<1, 1024, 0, stream>>>(cnt2, cur, N);
    }
    scatter_kernel<<<(E + 255) / 256, 256, 0, stream>>>(srcI, dstI, dist_t, unit_t, cur,
                                                        dist_s, unit_s, src_s, dst_s, E);

    int nblocksP = (N + NPB - 1) / NPB;
    int nblocksU = (N + 7) / 8;
    int nblocksH = (N + HPB - 1) / HPB;
    int eblocks = (E + EPB - 1) / EPB;
    for (int l = 0; l < 4; ++l) {
        phi_kernel<<<nblocksP, 128, 0, stream>>>(s_buf,
                                          msg_w1 + (size_t)l * HD * HD, msg_b1 + (size_t)l * HD,
                                          msg_w2 + (size_t)l * HD * H3, msg_b2 + (size_t)l * H3,
                                          phi_buf, N);
        hipMemcpyAsync(vn_buf, v_buf, (size_t)N * H3 * 4, hipMemcpyDeviceToDevice, stream);
        edge_kernel<<<eblocks, 512, 0, stream>>>(phi_buf, v_buf, dist_s, unit_s, src_s, dst_s,
                                                 rbf_w + (size_t)l * RD * H3, rbf_b + (size_t)l * H3,
                                                 s_buf, vn_buf, E);
        update_kernel<<<nblocksU, 128, 0, stream>>>(Um + (size_t)l * HD * HD, Vm + (size_t)l * HD * HD,
                                             upd_w1 + (size_t)l * 2 * HD * HD, upd_b1 + (size_t)l * HD,
                                             upd_w2 + (size_t)l * HD * H3, upd_b2 + (size_t)l * H3,
                                             s_buf, v_buf, vn_buf, condG, batch, (l < 3) ? 1 : 0, N);
    }
    heads_kernel<<<nblocksH, 128, 0, stream>>>(s_buf, hc_w1, hc_b1, hc_w2, hc_b2,
                                        ht_w1, ht_b1, ht_w2, ht_b2,
                                        (float*)d_out, (float*)d_out + (size_t)N * 3, N);
}

// Round 6
// 1465.183 us; speedup vs baseline: 1.4244x; 1.4244x over previous
//
#include <hip/hip_runtime.h>
#include <hip/hip_bf16.h>

#define HD 128
#define RD 64
#define H3 384

typedef float f32x4 __attribute__((ext_vector_type(4)));
typedef unsigned short us8 __attribute__((ext_vector_type(8)));
typedef __bf16 bf16x8 __attribute__((ext_vector_type(8)));

__device__ __forceinline__ float silu_f(float x) {
    return x / (1.0f + __expf(-x));
}
__device__ __forceinline__ unsigned short f2bf(float x) {
    __hip_bfloat16 h = __float2bfloat16(x);
    return *reinterpret_cast<unsigned short*>(&h);
}
__device__ __forceinline__ float bf2f(unsigned short u) {
    return __uint_as_float(((unsigned)u) << 16);
}
// 3-term split-precision MFMA bundle: (Ah+Al)@(Bh+Bl) ~= AhBh + AhBl + AlBh
__device__ __forceinline__ f32x4 mfma3(us8 ah, us8 al, us8 bh, us8 bl, f32x4 c) {
    bf16x8 AH = __builtin_bit_cast(bf16x8, ah);
    bf16x8 AL = __builtin_bit_cast(bf16x8, al);
    bf16x8 BH = __builtin_bit_cast(bf16x8, bh);
    bf16x8 BL = __builtin_bit_cast(bf16x8, bl);
    c = __builtin_amdgcn_mfma_f32_16x16x32_bf16(AH, BH, c, 0, 0, 0);
    c = __builtin_amdgcn_mfma_f32_16x16x32_bf16(AH, BL, c, 0, 0, 0);
    c = __builtin_amdgcn_mfma_f32_16x16x32_bf16(AL, BH, c, 0, 0, 0);
    return c;
}

// transpose + split f32 weights [K][OUT] -> bf16 hi/lo [OUT][K], nlay layers
__global__ void wprep_kernel(const float* __restrict__ src,
                             unsigned short* __restrict__ dhi, unsigned short* __restrict__ dlo,
                             int K, int OUT, int sStride, int dStride, int nlay) {
    int total = K * OUT;
    for (int idx = blockIdx.x * blockDim.x + threadIdx.x; idx < total * nlay;
         idx += gridDim.x * blockDim.x) {
        int lyr = idx / total, r = idx % total;
        int o = r / K, k = r % K;
        float x = src[(size_t)lyr * sStride + (size_t)k * OUT + o];
        unsigned short hi = f2bf(x);
        unsigned short lo = f2bf(x - bf2f(hi));
        dhi[(size_t)lyr * dStride + (size_t)o * K + k] = hi;
        dlo[(size_t)lyr * dStride + (size_t)o * K + k] = lo;
    }
}

// condG[g,h] = z[g]@z_w + z_b + t_emb[g]@t_w + t_b
__global__ __launch_bounds__(128) void cond_kernel(const float* __restrict__ z, const float* __restrict__ t,
                            const float* __restrict__ z_w, const float* __restrict__ z_b,
                            const float* __restrict__ t_w, const float* __restrict__ t_b,
                            float* __restrict__ condG) {
    int g = blockIdx.x;
    int k = threadIdx.x;
    __shared__ float zr[128];
    __shared__ float te[64];
    zr[k] = z[g * 128 + k];
    if (k < 32) {
        float f = __expf(-9.2103403719761836f * (float)k / 31.0f);
        float e = t[g] * f;
        te[k] = sinf(e);
        te[32 + k] = cosf(e);
    }
    __syncthreads();
    float acc = z_b[k] + t_b[k];
    #pragma unroll 8
    for (int i = 0; i < 128; ++i) acc += zr[i] * z_w[i * 128 + k];
    #pragma unroll 8
    for (int i = 0; i < 64; ++i) acc += te[i] * t_w[i * 128 + k];
    condG[g * 128 + k] = acc;
}

// s[n,h] = atom_embed[types[n], h] + condG[batch[n], h]
__global__ void init_kernel(const int* __restrict__ types, const float* __restrict__ emb,
                            const float* __restrict__ condG, const int* __restrict__ batch,
                            float* __restrict__ s, int N_) {
    int i = blockIdx.x * blockDim.x + threadIdx.x;
    if (i < N_ * HD) {
        int n = i >> 7;
        int k = i & 127;
        s[i] = emb[types[n] * HD + k] + condG[batch[n] * 128 + k];
    }
}

__global__ void geom_kernel(const float* __restrict__ coords, const int* __restrict__ srcI,
                            const int* __restrict__ dstI, const int* __restrict__ batch,
                            const float* __restrict__ lattice, const float* __restrict__ offs,
                            float* __restrict__ dist, float* __restrict__ unit, int E_) {
    int e = blockIdx.x * blockDim.x + threadIdx.x;
    if (e >= E_) return;
    int sn = srcI[e], dn = dstI[e];
    float f0 = coords[dn * 3 + 0] - coords[sn * 3 + 0] + offs[e * 3 + 0];
    float f1 = coords[dn * 3 + 1] - coords[sn * 3 + 1] + offs[e * 3 + 1];
    float f2 = coords[dn * 3 + 2] - coords[sn * 3 + 2] + offs[e * 3 + 2];
    const float* Lg = lattice + batch[sn] * 9;
    float c0 = f0 * Lg[0] + f1 * Lg[3] + f2 * Lg[6];
    float c1 = f0 * Lg[1] + f1 * Lg[4] + f2 * Lg[7];
    float c2 = f0 * Lg[2] + f1 * Lg[5] + f2 * Lg[8];
    float nrm = sqrtf(c0 * c0 + c1 * c1 + c2 * c2);
    dist[e] = fmaxf(nrm, 1e-8f);
    float inv = 1.0f / fmaxf(nrm, 1e-12f);
    unit[e * 3 + 0] = c0 * inv;
    unit[e * 3 + 1] = c1 * inv;
    unit[e * 3 + 2] = c2 * inv;
}

__global__ void hist_kernel(const int* __restrict__ dstI, int* __restrict__ cnt, int E_) {
    int e = blockIdx.x * blockDim.x + threadIdx.x;
    if (e < E_) atomicAdd(&cnt[dstI[e]], 1);
}

__global__ __launch_bounds__(1024) void scan_kernel(const int* __restrict__ cnt, int* __restrict__ cur, int n) {
    __shared__ int tmp[1024];
    __shared__ int carry_s;
    if (threadIdx.x == 0) carry_s = 0;
    __syncthreads();
    for (int base = 0; base < n; base += 1024) {
        int i = base + threadIdx.x;
        int x = (i < n) ? cnt[i] : 0;
        tmp[threadIdx.x] = x;
        __syncthreads();
        for (int off = 1; off < 1024; off <<= 1) {
            int y = (threadIdx.x >= off) ? tmp[threadIdx.x - off] : 0;
            __syncthreads();
            tmp[threadIdx.x] += y;
            __syncthreads();
        }
        if (i < n) cur[i] = carry_s + tmp[threadIdx.x] - x;
        __syncthreads();
        if (threadIdx.x == 0) carry_s += tmp[1023];
        __syncthreads();
    }
}

__global__ void scatter_kernel(const int* __restrict__ srcI, const int* __restrict__ dstI,
                               const float* __restrict__ dist, const float* __restrict__ unit,
                               int* __restrict__ cur,
                               float* __restrict__ dist_s, float* __restrict__ unit_s,
                               int* __restrict__ src_s, int* __restrict__ dst_s, int E_) {
    int e = blockIdx.x * blockDim.x + threadIdx.x;
    if (e >= E_) return;
    int d = dstI[e];
    int p = atomicAdd(&cur[d], 1);
    dist_s[p] = dist[e];
    unit_s[p * 3 + 0] = unit[e * 3 + 0];
    unit_s[p * 3 + 1] = unit[e * 3 + 1];
    unit_s[p * 3 + 2] = unit[e * 3 + 2];
    src_s[p] = srcI[e];
    dst_s[p] = d;
}

// ---- MFMA phi: phi = silu(s@w1+b1)@w2+b2, 32 nodes/block, 256 threads ----
#define PSA 136
__global__ __launch_bounds__(256, 2) void phi_mfma(
    const float* __restrict__ s,
    const unsigned short* __restrict__ w1h, const unsigned short* __restrict__ w1l,
    const float* __restrict__ b1,
    const unsigned short* __restrict__ w2h, const unsigned short* __restrict__ w2l,
    const float* __restrict__ b2,
    float* __restrict__ phi, int N_) {
    __shared__ unsigned short Ah[32 * PSA], Al[32 * PSA], Hh[32 * PSA], Hl[32 * PSA];
    const int tid = threadIdx.x;
    const int n0 = blockIdx.x * 32;
    for (int idx = tid; idx < 32 * 128; idx += 256) {
        int j = idx >> 7, k = idx & 127;
        int n = n0 + j; if (n >= N_) n = N_ - 1;
        float x = s[(size_t)n * 128 + k];
        unsigned short h = f2bf(x);
        Ah[j * PSA + k] = h;
        Al[j * PSA + k] = f2bf(x - bf2f(h));
    }
    __syncthreads();
    const int w = tid >> 6, l = tid & 63;
    const int lr = l & 15, lk = (l >> 4) << 3, rg0 = (l >> 4) << 2;
    const f32x4 zero4 = {0.0f, 0.0f, 0.0f, 0.0f};
    // GEMM1: [32x128]@[128x128]
    f32x4 acc1[2][2];
    #pragma unroll
    for (int rt = 0; rt < 2; ++rt)
        #pragma unroll
        for (int ci = 0; ci < 2; ++ci) acc1[rt][ci] = zero4;
    #pragma unroll
    for (int kt = 0; kt < 4; ++kt) {
        int kk = kt * 32 + lk;
        us8 bh[2], bl[2], ah[2], alo[2];
        #pragma unroll
        for (int ci = 0; ci < 2; ++ci) {
            int col = (w * 2 + ci) * 16 + lr;
            bh[ci] = *(const us8*)(w1h + (size_t)col * 128 + kk);
            bl[ci] = *(const us8*)(w1l + (size_t)col * 128 + kk);
        }
        #pragma unroll
        for (int rt = 0; rt < 2; ++rt) {
            ah[rt]  = *(const us8*)(Ah + (rt * 16 + lr) * PSA + kk);
            alo[rt] = *(const us8*)(Al + (rt * 16 + lr) * PSA + kk);
        }
        #pragma unroll
        for (int rt = 0; rt < 2; ++rt)
            #pragma unroll
            for (int ci = 0; ci < 2; ++ci)
                acc1[rt][ci] = mfma3(ah[rt], alo[rt], bh[ci], bl[ci], acc1[rt][ci]);
    }
    #pragma unroll
    for (int rt = 0; rt < 2; ++rt)
        #pragma unroll
        for (int ci = 0; ci < 2; ++ci) {
            int col = (w * 2 + ci) * 16 + lr;
            float bb = b1[col];
            #pragma unroll
            for (int rg = 0; rg < 4; ++rg) {
                int j = rt * 16 + rg0 + rg;
                float hv = silu_f(acc1[rt][ci][rg] + bb);
                unsigned short hh = f2bf(hv);
                Hh[j * PSA + col] = hh;
                Hl[j * PSA + col] = f2bf(hv - bf2f(hh));
            }
        }
    __syncthreads();
    // GEMM2: [32x128]@[128x384]
    f32x4 acc2[2][6];
    #pragma unroll
    for (int rt = 0; rt < 2; ++rt)
        #pragma unroll
        for (int ci = 0; ci < 6; ++ci) acc2[rt][ci] = zero4;
    #pragma unroll
    for (int kt = 0; kt < 4; ++kt) {
        int kk = kt * 32 + lk;
        us8 ah[2], alo[2];
        #pragma unroll
        for (int rt = 0; rt < 2; ++rt) {
            ah[rt]  = *(const us8*)(Hh + (rt * 16 + lr) * PSA + kk);
            alo[rt] = *(const us8*)(Hl + (rt * 16 + lr) * PSA + kk);
        }
        #pragma unroll
        for (int ci = 0; ci < 6; ++ci) {
            int col = (w * 6 + ci) * 16 + lr;
            us8 bh = *(const us8*)(w2h + (size_t)col * 128 + kk);
            us8 bl = *(const us8*)(w2l + (size_t)col * 128 + kk);
            #pragma unroll
            for (int rt = 0; rt < 2; ++rt)
                acc2[rt][ci] = mfma3(ah[rt], alo[rt], bh, bl, acc2[rt][ci]);
        }
    }
    #pragma unroll
    for (int rt = 0; rt < 2; ++rt)
        #pragma unroll
        for (int ci = 0; ci < 6; ++ci) {
            int col = (w * 6 + ci) * 16 + lr;
            float bb = b2[col];
            #pragma unroll
            for (int rg = 0; rg < 4; ++rg) {
                int j = rt * 16 + rg0 + rg;
                int n = n0 + j;
                if (n < N_) phi[(size_t)n * 384 + col] = acc2[rt][ci][rg] + bb;
            }
        }
}

// ---- MFMA update: 16 nodes/block, 256 threads ----
__global__ __launch_bounds__(256, 2) void upd_mfma(
    const unsigned short* __restrict__ Uh, const unsigned short* __restrict__ Ul,
    const unsigned short* __restrict__ Vh, const unsigned short* __restrict__ Vl,
    const unsigned short* __restrict__ w1h, const unsigned short* __restrict__ w1l,
    const float* __restrict__ b1,
    const unsigned short* __restrict__ w2h, const unsigned short* __restrict__ w2l,
    const float* __restrict__ b2,
    float* __restrict__ s, float* __restrict__ v, const float* __restrict__ dv,
    const float* __restrict__ condG, const int* __restrict__ batch, int addcond, int N_) {
    __shared__ unsigned short SMA[2 * 48 * 136];   // vn split; later A1(cat) + a1 splits
    __shared__ float UvL[48 * 132];
    __shared__ float VvL[48 * 132];                // later out384 [16][388]
    unsigned short* VNh = SMA;
    unsigned short* VNl = SMA + 48 * 136;
    unsigned short* A1h = SMA;
    unsigned short* A1l = SMA + 16 * 264;
    unsigned short* a1h = SMA + 32 * 264;
    unsigned short* a1l = SMA + 32 * 264 + 16 * 136;
    float* o384 = VvL;
    const int tid = threadIdx.x;
    const int n0 = blockIdx.x * 16;
    // stage vn = v + dv, rows r = c*16 + j
    for (int idx = tid; idx < 48 * 128; idx += 256) {
        int r = idx >> 7, k = idx & 127;
        int c = r >> 4, j = r & 15;
        int n = n0 + j; if (n >= N_) n = N_ - 1;
        size_t off = (size_t)n * 384 + c * 128 + k;
        float x = v[off] + dv[off];
        unsigned short h = f2bf(x);
        VNh[r * 136 + k] = h;
        VNl[r * 136 + k] = f2bf(x - bf2f(h));
    }
    __syncthreads();
    const int w = tid >> 6, l = tid & 63;
    const int lr = l & 15, lk = (l >> 4) << 3, rg0 = (l >> 4) << 2;
    const f32x4 zero4 = {0.0f, 0.0f, 0.0f, 0.0f};
    // Uv GEMM then Vv GEMM: [48x128]@[128x128]
    {
        f32x4 acc[3][2];
        #pragma unroll
        for (int rt = 0; rt < 3; ++rt) { acc[rt][0] = zero4; acc[rt][1] = zero4; }
        #pragma unroll
        for (int kt = 0; kt < 4; ++kt) {
            int kk = kt * 32 + lk;
            us8 bh[2], bl[2];
            #pragma unroll
            for (int ci = 0; ci < 2; ++ci) {
                int col = (w * 2 + ci) * 16 + lr;
                bh[ci] = *(const us8*)(Uh + (size_t)col * 128 + kk);
                bl[ci] = *(const us8*)(Ul + (size_t)col * 128 + kk);
            }
            #pragma unroll
            for (int rt = 0; rt < 3; ++rt) {
                us8 ah  = *(const us8*)(VNh + (rt * 16 + lr) * 136 + kk);
                us8 alo = *(const us8*)(VNl + (rt * 16 + lr) * 136 + kk);
                #pragma unroll
                for (int ci = 0; ci < 2; ++ci)
                    acc[rt][ci] = mfma3(ah, alo, bh[ci], bl[ci], acc[rt][ci]);
            }
        }
        #pragma unroll
        for (int rt = 0; rt < 3; ++rt)
            #pragma unroll
            for (int ci = 0; ci < 2; ++ci) {
                int col = (w * 2 + ci) * 16 + lr;
                #pragma unroll
                for (int rg = 0; rg < 4; ++rg)
                    UvL[(rt * 16 + rg0 + rg) * 132 + col] = acc[rt][ci][rg];
            }
        // V
        #pragma unroll
        for (int rt = 0; rt < 3; ++rt) { acc[rt][0] = zero4; acc[rt][1] = zero4; }
        #pragma unroll
        for (int kt = 0; kt < 4; ++kt) {
            int kk = kt * 32 + lk;
            us8 bh[2], bl[2];
            #pragma unroll
            for (int ci = 0; ci < 2; ++ci) {
                int col = (w * 2 + ci) * 16 + lr;
                bh[ci] = *(const us8*)(Vh + (size_t)col * 128 + kk);
                bl[ci] = *(const us8*)(Vl + (size_t)col * 128 + kk);
            }
            #pragma unroll
            for (int rt = 0; rt < 3; ++rt) {
                us8 ah  = *(const us8*)(VNh + (rt * 16 + lr) * 136 + kk);
                us8 alo = *(const us8*)(VNl + (rt * 16 + lr) * 136 + kk);
                #pragma unroll
                for (int ci = 0; ci < 2; ++ci)
                    acc[rt][ci] = mfma3(ah, alo, bh[ci], bl[ci], acc[rt][ci]);
            }
        }
        #pragma unroll
        for (int rt = 0; rt < 3; ++rt)
            #pragma unroll
            for (int ci = 0; ci < 2; ++ci) {
                int col = (w * 2 + ci) * 16 + lr;
                #pragma unroll
                for (int rg = 0; rg < 4; ++rg)
                    VvL[(rt * 16 + rg0 + rg) * 132 + col] = acc[rt][ci][rg];
            }
    }
    __syncthreads();
    // step D: Vn, dot; stage cat(s,Vn) split   (VN region now dead -> A1 region)
    float dotr[8];
    {
        int k = tid & 127;
        int jb = (tid >> 7) * 8;
        #pragma unroll
        for (int i = 0; i < 8; ++i) {
            int j = jb + i;
            float uv0 = UvL[j * 132 + k], uv1 = UvL[(16 + j) * 132 + k], uv2 = UvL[(32 + j) * 132 + k];
            float vv0 = VvL[j * 132 + k], vv1 = VvL[(16 + j) * 132 + k], vv2 = VvL[(32 + j) * 132 + k];
            dotr[i] = uv0 * vv0 + uv1 * vv1 + uv2 * vv2;
            float vnv = sqrtf(vv0 * vv0 + vv1 * vv1 + vv2 * vv2 + 1e-8f);
            int n = n0 + j; if (n >= N_) n = N_ - 1;
            float sv = s[(size_t)n * 128 + k];
            unsigned short h1 = f2bf(sv);
            A1h[j * 264 + k] = h1;
            A1l[j * 264 + k] = f2bf(sv - bf2f(h1));
            unsigned short h2 = f2bf(vnv);
            A1h[j * 264 + 128 + k] = h2;
            A1l[j * 264 + 128 + k] = f2bf(vnv - bf2f(h2));
        }
    }
    __syncthreads();
    // GEMM1: [16x256]@[256x128]
    {
        f32x4 acc[2]; acc[0] = zero4; acc[1] = zero4;
        #pragma unroll
        for (int kt = 0; kt < 8; ++kt) {
            int kk = kt * 32 + lk;
            us8 ah  = *(const us8*)(A1h + lr * 264 + kk);
            us8 alo = *(const us8*)(A1l + lr * 264 + kk);
            #pragma unroll
            for (int ci = 0; ci < 2; ++ci) {
                int col = (w * 2 + ci) * 16 + lr;
                us8 bh = *(const us8*)(w1h + (size_t)col * 256 + kk);
                us8 bl = *(const us8*)(w1l + (size_t)col * 256 + kk);
                acc[ci] = mfma3(ah, alo, bh, bl, acc[ci]);
            }
        }
        #pragma unroll
        for (int ci = 0; ci < 2; ++ci) {
            int col = (w * 2 + ci) * 16 + lr;
            float bb = b1[col];
            #pragma unroll
            for (int rg = 0; rg < 4; ++rg) {
                int j = rg0 + rg;
                float hv = silu_f(acc[ci][rg] + bb);
                unsigned short hh = f2bf(hv);
                a1h[j * 136 + col] = hh;
                a1l[j * 136 + col] = f2bf(hv - bf2f(hh));
            }
        }
    }
    __syncthreads();
    // GEMM2: [16x128]@[128x384] -> o384 (aliases VvL, dead since step D)
    {
        f32x4 acc[6];
        #pragma unroll
        for (int ci = 0; ci < 6; ++ci) acc[ci] = zero4;
        #pragma unroll
        for (int kt = 0; kt < 4; ++kt) {
            int kk = kt * 32 + lk;
            us8 ah  = *(const us8*)(a1h + lr * 136 + kk);
            us8 alo = *(const us8*)(a1l + lr * 136 + kk);
            #pragma unroll
            for (int ci = 0; ci < 6; ++ci) {
                int col = (w * 6 + ci) * 16 + lr;
                us8 bh = *(const us8*)(w2h + (size_t)col * 128 + kk);
                us8 bl = *(const us8*)(w2l + (size_t)col * 128 + kk);
                acc[ci] = mfma3(ah, alo, bh, bl, acc[ci]);
            }
        }
        #pragma unroll
        for (int ci = 0; ci < 6; ++ci) {
            int col = (w * 6 + ci) * 16 + lr;
            float bb = b2[col];
            #pragma unroll
            for (int rg = 0; rg < 4; ++rg) {
                int j = rg0 + rg;
                o384[j * 388 + col] = acc[ci][rg] + bb;
            }
        }
    }
    __syncthreads();
    // epilogue: v += a0*Uv (on vn), s += aH*dot + a2 (+cond)
    {
        int k = tid & 127;
        int jb = (tid >> 7) * 8;
        #pragma unroll
        for (int i = 0; i < 8; ++i) {
            int j = jb + i;
            int n = n0 + j;
            if (n >= N_) continue;
            float a0  = o384[j * 388 + k];
            float aH  = o384[j * 388 + 128 + k];
            float a2v = o384[j * 388 + 256 + k];
            #pragma unroll
            for (int c = 0; c < 3; ++c) {
                size_t off = (size_t)n * 384 + c * 128 + k;
                v[off] = v[off] + dv[off] + a0 * UvL[(c * 16 + j) * 132 + k];
            }
            float cadd = addcond ? condG[(size_t)batch[n] * 128 + k] : 0.0f;
            s[(size_t)n * 128 + k] += aH * dotr[i] + a2v + cadd;
        }
    }
}

// fused edge message on dst-sorted edges (round-3 form)
#define EPB 128
__global__ __launch_bounds__(512) void edge_kernel(
    const float* __restrict__ phi, const float* __restrict__ v,
    const float* __restrict__ dist_s, const float* __restrict__ unit_s,
    const int* __restrict__ src_s, const int* __restrict__ dst_s,
    const float* __restrict__ rw, const float* __restrict__ rb,
    float* __restrict__ s, float* __restrict__ dv, int E_) {
    __shared__ unsigned short w_lds[RD * H3];
    __shared__ float rbf_lds[4][4][RD];
    for (int i = threadIdx.x; i < RD * H3; i += 512) {
        w_lds[i] = f2bf(rw[i]);
    }
    int sub = threadIdx.x >> 7;
    int col = threadIdx.x & 127;
    float b0 = rb[col], b1 = rb[128 + col], b2 = rb[256 + col];
    int span0 = blockIdx.x * EPB + sub * 32;
    float as = 0.0f, ad0 = 0.0f, ad1 = 0.0f, ad2 = 0.0f;
    int rd = -1;
    for (int it = 0; it < 8; ++it) {
        int eb = span0 + it * 4;
        __syncthreads();
        {
            int r = col & 63;
            int jbase = col >> 6;
            #pragma unroll
            for (int jj = 0; jj < 2; ++jj) {
                int j = jbase + 2 * jj;
                int e = eb + j;
                float val = 0.0f;
                if (e < E_) {
                    float d = dist_s[e];
                    float c = 6.0f * (float)r / 63.0f;
                    float tt = d - c;
                    val = __expf(-(64.0f / 6.0f) * tt * tt);
                }
                rbf_lds[sub][j][r] = val;
            }
        }
        __syncthreads();
        float f[4][3] = {};
        #pragma unroll 4
        for (int r = 0; r < 64; ++r) {
            float w0 = bf2f(w_lds[r * 384 + col]);
            float w1 = bf2f(w_lds[r * 384 + 128 + col]);
            float w2 = bf2f(w_lds[r * 384 + 256 + col]);
            #pragma unroll
            for (int j = 0; j < 4; ++j) {
                float rbv = rbf_lds[sub][j][r];
                f[j][0] += rbv * w0;
                f[j][1] += rbv * w1;
                f[j][2] += rbv * w2;
            }
        }
        #pragma unroll
        for (int j = 0; j < 4; ++j) {
            int e = eb + j;
            if (e >= E_) break;
            int dn = dst_s[e];
            if (dn != rd) {
                if (rd >= 0) {
                    atomicAdd(&s[(size_t)rd * 128 + col], as);
                    atomicAdd(&dv[(size_t)rd * 384 + col], ad0);
                    atomicAdd(&dv[(size_t)rd * 384 + 128 + col], ad1);
                    atomicAdd(&dv[(size_t)rd * 384 + 256 + col], ad2);
                }
                as = ad0 = ad1 = ad2 = 0.0f;
                rd = dn;
            }
            int sn = src_s[e];
            const float* phr = phi + (size_t)sn * 384;
            const float* vr = v + (size_t)sn * 384;
            float x0 = phr[col] * (f[j][0] + b0);
            float x1 = phr[128 + col] * (f[j][1] + b1);
            float x2 = phr[256 + col] * (f[j][2] + b2);
            float u0 = unit_s[e * 3 + 0], u1 = unit_s[e * 3 + 1], u2 = unit_s[e * 3 + 2];
            as += x0;
            ad0 += x1 * vr[col] + x2 * u0;
            ad1 += x1 * vr[128 + col] + x2 * u1;
            ad2 += x1 * vr[256 + col] + x2 * u2;
        }
    }
    if (rd >= 0) {
        atomicAdd(&s[(size_t)rd * 128 + col], as);
        atomicAdd(&dv[(size_t)rd * 384 + col], ad0);
        atomicAdd(&dv[(size_t)rd * 384 + 128 + col], ad1);
        atomicAdd(&dv[(size_t)rd * 384 + 256 + col], ad2);
    }
}

// output heads: 8 nodes per block (round-3 form)
#define HPB 8
__global__ __launch_bounds__(128, 4) void heads_kernel(
    const float* __restrict__ s,
    const float* __restrict__ hc_w1, const float* __restrict__ hc_b1,
    const float* __restrict__ hc_w2, const float* __restrict__ hc_b2,
    const float* __restrict__ ht_w1, const float* __restrict__ ht_b1,
    const float* __restrict__ ht_w2, const float* __restrict__ ht_b2,
    float* __restrict__ outc, float* __restrict__ outt, int N_) {
    int n0 = blockIdx.x * HPB;
    int k = threadIdx.x;
    __shared__ float sr[HPB][128];
    __shared__ float h1[HPB][128];
    __shared__ float h2[HPB][128];
    #pragma unroll
    for (int j = 0; j < HPB; ++j) {
        int n = n0 + j;
        sr[j][k] = (n < N_) ? s[(size_t)n * 128 + k] : 0.0f;
    }
    __syncthreads();
    float a[HPB], b[HPB];
    #pragma unroll
    for (int j = 0; j < HPB; ++j) { a[j] = hc_b1[k]; b[j] = ht_b1[k]; }
    for (int h = 0; h < 128; h += 4) {
        float wa0 = hc_w1[h * 128 + k],       wa1 = hc_w1[(h + 1) * 128 + k];
        float wa2 = hc_w1[(h + 2) * 128 + k], wa3 = hc_w1[(h + 3) * 128 + k];
        float wb0 = ht_w1[h * 128 + k],       wb1 = ht_w1[(h + 1) * 128 + k];
        float wb2 = ht_w1[(h + 2) * 128 + k], wb3 = ht_w1[(h + 3) * 128 + k];
        #pragma unroll
        for (int j = 0; j < HPB; ++j) {
            const float4 x = *reinterpret_cast<const float4*>(&sr[j][h]);
            a[j] = fmaf(x.w, wa3, fmaf(x.z, wa2, fmaf(x.y, wa1, fmaf(x.x, wa0, a[j]))));
            b[j] = fmaf(x.w, wb3, fmaf(x.z, wb2, fmaf(x.y, wb1, fmaf(x.x, wb0, b[j]))));
        }
    }
    #pragma unroll
    for (int j = 0; j < HPB; ++j) {
        h1[j][k] = silu_f(a[j]);
        h2[j][k] = silu_f(b[j]);
    }
    __syncthreads();
    if (k < 101) {
        for (int j = 0; j < HPB; ++j) {
            int n = n0 + j;
            if (n >= N_) break;
            float c = ht_b2[k];
            #pragma unroll 4
            for (int h = 0; h < 128; ++h) c += h2[j][h] * ht_w2[h * 101 + k];
            outt[(size_t)n * 101 + k] = c;
        }
    }
    if (k < 3) {
        for (int j = 0; j < HPB; ++j) {
            int n = n0 + j;
            if (n >= N_) break;
            float c = hc_b2[k];
            #pragma unroll 4
            for (int h = 0; h < 128; ++h) c += h1[j][h] * hc_w2[h * 3 + k];
            outc[(size_t)n * 3 + k] = c;
        }
    }
}

extern "C" void kernel_launch(void* const* d_in, const int* in_sizes, int n_in,
                              void* d_out, int out_size, void* d_ws, size_t ws_size,
                              hipStream_t stream) {
    const float* coords  = (const float*)d_in[0];
    const int*   types   = (const int*)d_in[1];
    const float* z       = (const float*)d_in[2];
    const float* t       = (const float*)d_in[3];
    const int*   eidx    = (const int*)d_in[4];
    const int*   batch   = (const int*)d_in[5];
    const float* lattice = (const float*)d_in[6];
    const float* offs    = (const float*)d_in[7];
    const float* aemb    = (const float*)d_in[8];
    const float* z_w     = (const float*)d_in[9];
    const float* z_b     = (const float*)d_in[10];
    const float* t_w     = (const float*)d_in[11];
    const float* t_b     = (const float*)d_in[12];
    const float* msg_w1  = (const float*)d_in[13];
    const float* msg_b1  = (const float*)d_in[14];
    const float* msg_w2  = (const float*)d_in[15];
    const float* msg_b2  = (const float*)d_in[16];
    const float* rbf_w   = (const float*)d_in[17];
    const float* rbf_b   = (const float*)d_in[18];
    const float* Um      = (const float*)d_in[19];
    const float* Vm      = (const float*)d_in[20];
    const float* upd_w1  = (const float*)d_in[21];
    const float* upd_b1  = (const float*)d_in[22];
    const float* upd_w2  = (const float*)d_in[23];
    const float* upd_b2  = (const float*)d_in[24];
    const float* hc_w1   = (const float*)d_in[25];
    const float* hc_b1   = (const float*)d_in[26];
    const float* hc_w2   = (const float*)d_in[27];
    const float* hc_b2   = (const float*)d_in[28];
    const float* ht_w1   = (const float*)d_in[29];
    const float* ht_b1   = (const float*)d_in[30];
    const float* ht_w2   = (const float*)d_in[31];
    const float* ht_b2   = (const float*)d_in[32];

    const int N = in_sizes[1];
    const int G = in_sizes[3];
    const int E = in_sizes[4] / 2;
    const int* srcI = eidx;
    const int* dstI = eidx + E;

    char* ws = (char*)d_ws;
    auto alloc = [&](size_t bytes) {
        char* p = ws;
        ws += (bytes + 255) & ~(size_t)255;
        return p;
    };
    float* s_buf   = (float*)alloc((size_t)N * HD * 4);
    float* v_buf   = (float*)alloc((size_t)N * H3 * 4);
    float* dv_buf  = (float*)alloc((size_t)N * H3 * 4);
    float* phi_buf = (float*)alloc((size_t)N * H3 * 4);
    float* condG   = (float*)alloc((size_t)G * HD * 4);
    float* dist_s  = (float*)alloc((size_t)E * 4);
    float* unit_s  = (float*)alloc((size_t)E * 3 * 4);
    int*   src_s   = (int*)alloc((size_t)E * 4);
    int*   dst_s   = (int*)alloc((size_t)E * 4);
    int*   cur     = (int*)alloc((size_t)N * 4);
    unsigned short* wpr = (unsigned short*)alloc((size_t)4 * 360448 * 2);
    // per-layer short offsets inside wpr (layer stride 360448):
    // pw1 h/l: 0 / 16384 ; pw2 h/l: 32768 / 81920 ; uw1 h/l: 131072 / 163840 ;
    // uw2 h/l: 196608 / 245760 ; U h/l: 294912 / 311296 ; V h/l: 327680 / 344064
    const size_t LS = 360448;
    float* dist_t  = phi_buf;
    float* unit_t  = phi_buf + E;

    hipMemsetAsync(v_buf, 0, (size_t)N * H3 * 4, stream);
    hipMemsetAsync(cur, 0, (size_t)N * 4, stream);
    cond_kernel<<<G, 128, 0, stream>>>(z, t, z_w, z_b, t_w, t_b, condG);
    init_kernel<<<(N * HD + 255) / 256, 256, 0, stream>>>(types, aemb, condG, batch, s_buf, N);
    geom_kernel<<<(E + 255) / 256, 256, 0, stream>>>(coords, srcI, dstI, batch, lattice, offs, dist_t, unit_t, E);
    hist_kernel<<<(E + 255) / 256, 256, 0, stream>>>(dstI, cur, E);
    {
        int* cnt2 = (int*)(phi_buf + 4 * (size_t)E);
        hipMemcpyAsync(cnt2, cur, (size_t)N * 4, hipMemcpyDeviceToDevice, stream);
        scan_kernel<<<1, 1024, 0, stream>>>(cnt2, cur, N);
    }
    scatter_kernel<<<(E + 255) / 256, 256, 0, stream>>>(srcI, dstI, dist_t, unit_t, cur,
                                                        dist_s, unit_s, src_s, dst_s, E);
    // weight prep (transpose + hi/lo split), 4 layers each
    wprep_kernel<<<256, 256, 0, stream>>>(msg_w1, wpr + 0,      wpr + 16384,  128, 128, 16384, (int)LS, 4);
    wprep_kernel<<<768, 256, 0, stream>>>(msg_w2, wpr + 32768,  wpr + 81920,  128, 384, 49152, (int)LS, 4);
    wprep_kernel<<<512, 256, 0, stream>>>(upd_w1, wpr + 131072, wpr + 163840, 256, 128, 32768, (int)LS, 4);
    wprep_kernel<<<768, 256, 0, stream>>>(upd_w2, wpr + 196608, wpr + 245760, 128, 384, 49152, (int)LS, 4);
    wprep_kernel<<<256, 256, 0, stream>>>(Um,     wpr + 294912, wpr + 311296, 128, 128, 16384, (int)LS, 4);
    wprep_kernel<<<256, 256, 0, stream>>>(Vm,     wpr + 327680, wpr + 344064, 128, 128, 16384, (int)LS, 4);

    int eblocks = (E + EPB - 1) / EPB;
    int pblocks = (N + 31) / 32;
    int ublocks = (N + 15) / 16;
    int hblocks = (N + HPB - 1) / HPB;
    for (int l = 0; l < 4; ++l) {
        const unsigned short* L = wpr + (size_t)l * LS;
        phi_mfma<<<pblocks, 256, 0, stream>>>(s_buf,
                L + 0, L + 16384, msg_b1 + (size_t)l * HD,
                L + 32768, L + 81920, msg_b2 + (size_t)l * H3,
                phi_buf, N);
        hipMemsetAsync(dv_buf, 0, (size_t)N * H3 * 4, stream);
        edge_kernel<<<eblocks, 512, 0, stream>>>(phi_buf, v_buf, dist_s, unit_s, src_s, dst_s,
                                                 rbf_w + (size_t)l * RD * H3, rbf_b + (size_t)l * H3,
                                                 s_buf, dv_buf, E);
        upd_mfma<<<ublocks, 256, 0, stream>>>(
                L + 294912, L + 311296, L + 327680, L + 344064,
                L + 131072, L + 163840, upd_b1 + (size_t)l * HD,
                L + 196608, L + 245760, upd_b2 + (size_t)l * H3,
                s_buf, v_buf, dv_buf, condG, batch, (l < 3) ? 1 : 0, N);
    }
    heads_kernel<<<hblocks, 128, 0, stream>>>(s_buf, hc_w1, hc_b1, hc_w2, hc_b2,
                                        ht_w1, ht_b1, ht_w2, ht_b2,
                                        (float*)d_out, (float*)d_out + (size_t)N * 3, N);
}